// Round 6
// baseline (158.516 us; speedup 1.0000x reference)
//
#include <hip/hip_runtime.h>
#include <hip/hip_bf16.h>

typedef unsigned short u16;
typedef u16 u16x4 __attribute__((ext_vector_type(4)));
typedef u16 u16x8 __attribute__((ext_vector_type(8)));
typedef __bf16 bf16x8 __attribute__((ext_vector_type(8)));
typedef float f32x4 __attribute__((ext_vector_type(4)));

static __device__ __forceinline__ u16 f2bf(float f) {
  return __builtin_bit_cast(u16, __float2bfloat16(f));   // RTNE; pairs into v_cvt_pk_bf16_f32
}

// async global->LDS, 16B per lane. LDS dest = wave-uniform base + lane*16.
static __device__ __forceinline__ void gload16(const u16* g, u16* l) {
  __builtin_amdgcn_global_load_lds(
      (const __attribute__((address_space(1))) unsigned*)g,
      (__attribute__((address_space(3))) unsigned*)l, 16, 0, 0);
}

#define WAIT4_BAR() asm volatile("s_waitcnt vmcnt(4)\ns_barrier" ::: "memory")
#define WAIT0_BAR() asm volatile("s_waitcnt vmcnt(0)\ns_barrier" ::: "memory")
#define BAR()       asm volatile("s_barrier" ::: "memory")

// ---------------- x f32 -> bf16 ----------------
__global__ __launch_bounds__(256) void cvt_x_kernel(const float* __restrict__ in,
                                                    u16* __restrict__ out) {
  int i = blockIdx.x * 256 + threadIdx.x;          // 8 elems per thread
  const float4* p = reinterpret_cast<const float4*>(in) + (size_t)i * 2;
  float4 a = p[0], b = p[1];
  u16x8 o;
  o[0] = f2bf(a.x); o[1] = f2bf(a.y); o[2] = f2bf(a.z); o[3] = f2bf(a.w);
  o[4] = f2bf(b.x); o[5] = f2bf(b.y); o[6] = f2bf(b.z); o[7] = f2bf(b.w);
  reinterpret_cast<u16x8*>(out)[i] = o;
}

// ---------------- W [768][2304] f32 -> WbT [2304][768] bf16 ----------------
__global__ __launch_bounds__(256) void cvt_wT_kernel(const float* __restrict__ W,
                                                     u16* __restrict__ WT) {
  int n  = blockIdx.x * 256 + threadIdx.x;   // 0..2303 (gridDim.x = 9)
  int k0 = blockIdx.y * 4;                   // gridDim.y = 192
  u16x4 o;
#pragma unroll
  for (int j = 0; j < 4; ++j) o[j] = f2bf(W[(size_t)(k0 + j) * 2304 + n]);
  *reinterpret_cast<u16x4*>(WT + (size_t)n * 768 + k0) = o;
}

// ---------------- QKV GEMM: [8192x768] @ [768x2304] + bias ----------------
// 2-deep counted-vmcnt pipeline: stage(t+2) in flight across barriers, vmcnt
// never drained to 0 in the main loop (T4). K=768 -> 24 chunks of BK=32.
// writes q[bh][t][d], k[bh][t][d], vT[bh][d][t]  (all bf16)

static __device__ __forceinline__ void gemm_compute(
    const u16* __restrict__ as, const u16* __restrict__ bs,
    int wm, int wn, int l16, int g, f32x4 (&acc)[4][4]) {
  bf16x8 af[4], bfr[4];
#pragma unroll
  for (int mi = 0; mi < 4; ++mi)
    af[mi] = __builtin_bit_cast(bf16x8,
        *reinterpret_cast<const u16x8*>(as + (wm + mi * 16 + l16) * 32 + g * 8));
#pragma unroll
  for (int ni = 0; ni < 4; ++ni)
    bfr[ni] = __builtin_bit_cast(bf16x8,
        *reinterpret_cast<const u16x8*>(bs + (wn + ni * 16 + l16) * 32 + g * 8));
#pragma unroll
  for (int mi = 0; mi < 4; ++mi)
#pragma unroll
    for (int ni = 0; ni < 4; ++ni)
      acc[mi][ni] = __builtin_amdgcn_mfma_f32_16x16x32_bf16(af[mi], bfr[ni], acc[mi][ni], 0, 0, 0);
}

__global__ __launch_bounds__(256, 4) void gemm_qkv_kernel(
    const u16* __restrict__ A, const u16* __restrict__ Bt,
    const float* __restrict__ bias,
    u16* __restrict__ qb, u16* __restrict__ kb, u16* __restrict__ vTb) {
  __shared__ __align__(16) u16 as0[128 * 32], as1[128 * 32];
  __shared__ __align__(16) u16 bs0[128 * 32], bs1[128 * 32];
  const int K = 768;
  int tid = threadIdx.x;
  int lane = tid & 63;
  int wave = tid >> 6;

  int m0 = blockIdx.x * 128;       // gridDim.x = 64 (m%8==XCD -> per-XCD L2-fit footprint)
  int n0 = blockIdx.y * 128;       // gridDim.y = 18

  int wm = (wave >> 1) * 64;
  int wn = (wave & 1) * 64;
  int l16 = lane & 15, g = lane >> 4;

  // staging: wave w owns tile rows [w*32, w*32+32), 2 instrs of 16 rows each.
  const u16* gA = A  + (size_t)(m0 + wave * 32 + (lane >> 2)) * K + (lane & 3) * 8;
  const u16* gB = Bt + (size_t)(n0 + wave * 32 + (lane >> 2)) * K + (lane & 3) * 8;
  int lofs = wave * 1024;   // elems; +512 for second 16 rows

  f32x4 acc[4][4];
#pragma unroll
  for (int mi = 0; mi < 4; ++mi)
#pragma unroll
    for (int ni = 0; ni < 4; ++ni) acc[mi][ni] = (f32x4){0.f, 0.f, 0.f, 0.f};

#define STAGE(Abuf, Bbuf, kk)                          \
  do {                                                 \
    gload16(gA + (kk),          Abuf + lofs);          \
    gload16(gA + (kk) + 16 * K, Abuf + lofs + 512);    \
    gload16(gB + (kk),          Bbuf + lofs);          \
    gload16(gB + (kk) + 16 * K, Bbuf + lofs + 512);    \
  } while (0)

  // prologue: chunks 0,1 in flight (8 loads)
  STAGE(as0, bs0, 0);
  STAGE(as1, bs1, 32);
  for (int j = 0; j < 11; ++j) {
    int k0 = j * 64;
    WAIT4_BAR();                       // chunk 2j landed (newest 4 stay in flight)
    gemm_compute(as0, bs0, wm, wn, l16, g, acc);
    BAR();                             // everyone done reading as0/bs0
    STAGE(as0, bs0, k0 + 64);          // chunk 2j+2
    WAIT4_BAR();                       // chunk 2j+1 landed
    gemm_compute(as1, bs1, wm, wn, l16, g, acc);
    BAR();
    STAGE(as1, bs1, k0 + 96);          // chunk 2j+3
  }
  // peel: chunks 22 (k=704, as0) and 23 (k=736, as1)
  WAIT4_BAR();
  gemm_compute(as0, bs0, wm, wn, l16, g, acc);
  WAIT0_BAR();
  gemm_compute(as1, bs1, wm, wn, l16, g, acc);
#undef STAGE

  // epilogue: bias + scatter to q/k/vT (bf16)
  int tbase = m0 & 1023;
  int b = m0 >> 10;
  int g4 = g * 4;
#pragma unroll
  for (int ni = 0; ni < 4; ++ni) {
    int n = n0 + wn + ni * 16 + l16;
    float bv = bias[n];
    int region = n / 768;
    int c = n - region * 768;
    int h = c >> 6, d = c & 63;
    int bh = b * 12 + h;
#pragma unroll
    for (int mi = 0; mi < 4; ++mi) {
      int t0 = tbase + wm + mi * 16 + g4;
      if (region == 2) {
        u16x4 pv;
#pragma unroll
        for (int r = 0; r < 4; ++r) pv[r] = f2bf(acc[mi][ni][r] + bv);
        *reinterpret_cast<u16x4*>(vTb + ((size_t)bh * 64 + d) * 1024 + t0) = pv;
      } else {
        u16* dst = (region == 0) ? qb : kb;
#pragma unroll
        for (int r = 0; r < 4; ++r)
          dst[((size_t)bh * 1024 + t0 + r) * 64 + d] = f2bf(acc[mi][ni][r] + bv);
      }
    }
  }
}

// ---------------- causal relu attention ----------------
// y[b,h,q,:] = sum_{k<=q} relu(scale * q.k) * v[k]
// 16 q-rows per wave (6144 waves total). Pipelined: loads(t+1) -> pack P(t)
// -> QK^T(t+1) (fills LDS write->read gap) -> PV(t) -> V-load(t+1).
__global__ __launch_bounds__(256) void attn_kernel(
    const u16* __restrict__ qb, const u16* __restrict__ kb,
    const u16* __restrict__ vTb, float* __restrict__ out) {
  __shared__ __align__(16) u16 plds[4][16 * 40];
  int lane = threadIdx.x & 63;
  int wave = threadIdx.x >> 6;
  int bh = blockIdx.x;                            // 0..95
  int q0 = (15 - blockIdx.y) * 64 + wave * 16;    // heaviest blocks first
  int b = bh / 12, h = bh - b * 12;
  const u16* Q  = qb  + (size_t)bh * 65536;
  const u16* Kp = kb  + (size_t)bh * 65536;
  const u16* Vt = vTb + (size_t)bh * 65536;
  int l16 = lane & 15, g = lane >> 4;
  u16* pw = &plds[wave][0];

  bf16x8 qf[2];
#pragma unroll
  for (int ks = 0; ks < 2; ++ks)
    qf[ks] = __builtin_bit_cast(bf16x8,
        *reinterpret_cast<const u16x8*>(Q + (q0 + l16) * 64 + ks * 32 + g * 8));

  f32x4 y[4];
#pragma unroll
  for (int ni = 0; ni < 4; ++ni) y[ni] = (f32x4){0.f, 0.f, 0.f, 0.f};

  int ktmax = q0 >> 5;                  // 32-key tiles; q0 is a multiple of 16
  int qrel = (q0 & 31) + l16;           // q-row index relative to the diag tile base

  // prologue: K/V of tile 0, then S^T(0)
  u16x8 kn[4], vcur[4];
#pragma unroll
  for (int kj = 0; kj < 2; ++kj)
#pragma unroll
    for (int ks = 0; ks < 2; ++ks)
      kn[kj * 2 + ks] = *reinterpret_cast<const u16x8*>(
          Kp + (kj * 16 + l16) * 64 + ks * 32 + g * 8);
#pragma unroll
  for (int ni = 0; ni < 4; ++ni)
    vcur[ni] = *reinterpret_cast<const u16x8*>(Vt + (ni * 16 + l16) * 1024 + g * 8);

  // S^T lane layout: q = l16 (col), key = kj*16 + g*4 + r (row)
  f32x4 s2c[2];
#pragma unroll
  for (int kj = 0; kj < 2; ++kj) s2c[kj] = (f32x4){0.f, 0.f, 0.f, 0.f};
#pragma unroll
  for (int ks = 0; ks < 2; ++ks)
#pragma unroll
    for (int kj = 0; kj < 2; ++kj)
      s2c[kj] = __builtin_amdgcn_mfma_f32_16x16x32_bf16(
          __builtin_bit_cast(bf16x8, kn[kj * 2 + ks]), qf[ks], s2c[kj], 0, 0, 0);

  for (int kt = 0; kt <= ktmax; ++kt) {
    bool notlast = (kt < ktmax);

    // 1) issue next tile's K loads
    if (notlast) {
      int kb2 = (kt + 1) << 5;
#pragma unroll
      for (int kj = 0; kj < 2; ++kj)
#pragma unroll
        for (int ks = 0; ks < 2; ++ks)
          kn[kj * 2 + ks] = *reinterpret_cast<const u16x8*>(
              Kp + (kb2 + kj * 16 + l16) * 64 + ks * 32 + g * 8);
    }

    // 2) pack P(t): scale, relu, diag mask; LDS write (b64 per kj)
    bool diag = !notlast;
#pragma unroll
    for (int kj = 0; kj < 2; ++kj) {
      u16x4 pv;
#pragma unroll
      for (int r = 0; r < 4; ++r) {
        float v = fmaxf(s2c[kj][r] * 0.125f, 0.f);
        if (diag && (kj * 16 + g * 4 + r > qrel)) v = 0.f;
        pv[r] = f2bf(v);
      }
      *reinterpret_cast<u16x4*>(pw + l16 * 40 + kj * 16 + g * 4) = pv;
    }

    __builtin_amdgcn_s_setprio(1);
    // 3) QK^T(t+1) — fills the LDS write->read latency window
    f32x4 s2n[2];
    if (notlast) {
#pragma unroll
      for (int kj = 0; kj < 2; ++kj) s2n[kj] = (f32x4){0.f, 0.f, 0.f, 0.f};
#pragma unroll
      for (int ks = 0; ks < 2; ++ks)
#pragma unroll
        for (int kj = 0; kj < 2; ++kj)
          s2n[kj] = __builtin_amdgcn_mfma_f32_16x16x32_bf16(
              __builtin_bit_cast(bf16x8, kn[kj * 2 + ks]), qf[ks], s2n[kj], 0, 0, 0);
    }

    // 4) read P(t), PV(t)
    bf16x8 pa = __builtin_bit_cast(bf16x8,
        *reinterpret_cast<const u16x8*>(pw + l16 * 40 + g * 8));
#pragma unroll
    for (int ni = 0; ni < 4; ++ni)
      y[ni] = __builtin_amdgcn_mfma_f32_16x16x32_bf16(
          pa, __builtin_bit_cast(bf16x8, vcur[ni]), y[ni], 0, 0, 0);
    __builtin_amdgcn_s_setprio(0);

    // 5) V(t+1) load after last vcur use; rotate S
    if (notlast) {
      int kb2 = (kt + 1) << 5;
#pragma unroll
      for (int ni = 0; ni < 4; ++ni)
        vcur[ni] = *reinterpret_cast<const u16x8*>(Vt + (ni * 16 + l16) * 1024 + kb2 + g * 8);
#pragma unroll
      for (int kj = 0; kj < 2; ++kj) s2c[kj] = s2n[kj];
    }
  }

  // out[b, t, h*64+d] f32; q row = g*4 + r
  float* outp = out + (size_t)b * 1024 * 768 + (size_t)h * 64;
#pragma unroll
  for (int r = 0; r < 4; ++r) {
    int t = q0 + g * 4 + r;
#pragma unroll
    for (int ni = 0; ni < 4; ++ni)
      outp[(size_t)t * 768 + ni * 16 + l16] = y[ni][r];
  }
}

extern "C" void kernel_launch(void* const* d_in, const int* in_sizes, int n_in,
                              void* d_out, int out_size, void* d_ws, size_t ws_size,
                              hipStream_t stream) {
  const float* x    = (const float*)d_in[0];
  const float* W    = (const float*)d_in[1];
  const float* bias = (const float*)d_in[2];
  float* out = (float*)d_out;
  char* ws = (char*)d_ws;

  // ws layout (bytes): xb 12.58MB | WbT 3.54MB | qb 12.58MB | kb 12.58MB | vTb 12.58MB
  u16* xb  = (u16*)(ws);
  u16* WbT = (u16*)(ws + 12582912);
  u16* qb  = (u16*)(ws + 16121856);
  u16* kb  = (u16*)(ws + 28704768);
  u16* vTb = (u16*)(ws + 41287680);

  hipLaunchKernelGGL(cvt_x_kernel, dim3(3072), dim3(256), 0, stream, x, xb);
  hipLaunchKernelGGL(cvt_wT_kernel, dim3(9, 192), dim3(256), 0, stream, W, WbT);
  hipLaunchKernelGGL(gemm_qkv_kernel, dim3(64, 18), dim3(256), 0, stream,
                     xb, WbT, bias, qb, kb, vTb);
  hipLaunchKernelGGL(attn_kernel, dim3(96, 16), dim3(256), 0, stream, qb, kb, vTb, out);
}

// Round 7
// 116.430 us; speedup vs baseline: 1.3615x; 1.3615x over previous
//
#include <hip/hip_runtime.h>
#include <hip/hip_bf16.h>

typedef unsigned short u16;
typedef u16 u16x4 __attribute__((ext_vector_type(4)));
typedef u16 u16x8 __attribute__((ext_vector_type(8)));
typedef __bf16 bf16x8 __attribute__((ext_vector_type(8)));
typedef float f32x4 __attribute__((ext_vector_type(4)));

static __device__ __forceinline__ u16 f2bf(float f) {
  return __builtin_bit_cast(u16, __float2bfloat16(f));   // RTNE; pairs into v_cvt_pk_bf16_f32
}

// async global->LDS, 16B per lane. LDS dest = wave-uniform base + lane*16.
static __device__ __forceinline__ void gload16(const u16* g, u16* l) {
  __builtin_amdgcn_global_load_lds(
      (const __attribute__((address_space(1))) unsigned*)g,
      (__attribute__((address_space(3))) unsigned*)l, 16, 0, 0);
}

#define WAIT4_BAR() asm volatile("s_waitcnt vmcnt(4)\ns_barrier" ::: "memory")
#define WAIT0_BAR() asm volatile("s_waitcnt vmcnt(0)\ns_barrier" ::: "memory")
#define BAR()       asm volatile("s_barrier" ::: "memory")

// ---------------- x f32 -> bf16 ----------------
__global__ __launch_bounds__(256) void cvt_x_kernel(const float* __restrict__ in,
                                                    u16* __restrict__ out) {
  int i = blockIdx.x * 256 + threadIdx.x;          // 8 elems per thread
  const float4* p = reinterpret_cast<const float4*>(in) + (size_t)i * 2;
  float4 a = p[0], b = p[1];
  u16x8 o;
  o[0] = f2bf(a.x); o[1] = f2bf(a.y); o[2] = f2bf(a.z); o[3] = f2bf(a.w);
  o[4] = f2bf(b.x); o[5] = f2bf(b.y); o[6] = f2bf(b.z); o[7] = f2bf(b.w);
  reinterpret_cast<u16x8*>(out)[i] = o;
}

// ---------------- W [768][2304] f32 -> WbT [2304][768] bf16 ----------------
__global__ __launch_bounds__(256) void cvt_wT_kernel(const float* __restrict__ W,
                                                     u16* __restrict__ WT) {
  int n  = blockIdx.x * 256 + threadIdx.x;   // 0..2303 (gridDim.x = 9)
  int k0 = blockIdx.y * 4;                   // gridDim.y = 192
  u16x4 o;
#pragma unroll
  for (int j = 0; j < 4; ++j) o[j] = f2bf(W[(size_t)(k0 + j) * 2304 + n]);
  *reinterpret_cast<u16x4*>(WT + (size_t)n * 768 + k0) = o;
}

// ---------------- QKV GEMM: [8192x768] @ [768x2304] + bias ----------------
// 2-deep counted-vmcnt pipeline (T4): stage(t+2) in flight across barriers,
// vmcnt never drained to 0 in the main loop. K=768 -> 24 chunks of BK=32.
// writes q[bh][t][d], k[bh][t][d], vT[bh][d][t]  (all bf16)

static __device__ __forceinline__ void gemm_compute(
    const u16* __restrict__ as, const u16* __restrict__ bs,
    int wm, int wn, int l16, int g, f32x4 (&acc)[4][4]) {
  bf16x8 af[4], bfr[4];
#pragma unroll
  for (int mi = 0; mi < 4; ++mi)
    af[mi] = __builtin_bit_cast(bf16x8,
        *reinterpret_cast<const u16x8*>(as + (wm + mi * 16 + l16) * 32 + g * 8));
#pragma unroll
  for (int ni = 0; ni < 4; ++ni)
    bfr[ni] = __builtin_bit_cast(bf16x8,
        *reinterpret_cast<const u16x8*>(bs + (wn + ni * 16 + l16) * 32 + g * 8));
#pragma unroll
  for (int mi = 0; mi < 4; ++mi)
#pragma unroll
    for (int ni = 0; ni < 4; ++ni)
      acc[mi][ni] = __builtin_amdgcn_mfma_f32_16x16x32_bf16(af[mi], bfr[ni], acc[mi][ni], 0, 0, 0);
}

__global__ __launch_bounds__(256, 4) void gemm_qkv_kernel(
    const u16* __restrict__ A, const u16* __restrict__ Bt,
    const float* __restrict__ bias,
    u16* __restrict__ qb, u16* __restrict__ kb, u16* __restrict__ vTb) {
  __shared__ __align__(16) u16 as0[128 * 32], as1[128 * 32];
  __shared__ __align__(16) u16 bs0[128 * 32], bs1[128 * 32];
  const int K = 768;
  int tid = threadIdx.x;
  int lane = tid & 63;
  int wave = tid >> 6;

  int m0 = blockIdx.x * 128;       // gridDim.x = 64 (m%8==XCD -> per-XCD L2-fit footprint)
  int n0 = blockIdx.y * 128;       // gridDim.y = 18

  int wm = (wave >> 1) * 64;
  int wn = (wave & 1) * 64;
  int l16 = lane & 15, g = lane >> 4;

  // staging: wave w owns tile rows [w*32, w*32+32), 2 instrs of 16 rows each.
  const u16* gA = A  + (size_t)(m0 + wave * 32 + (lane >> 2)) * K + (lane & 3) * 8;
  const u16* gB = Bt + (size_t)(n0 + wave * 32 + (lane >> 2)) * K + (lane & 3) * 8;
  int lofs = wave * 1024;   // elems; +512 for second 16 rows

  f32x4 acc[4][4];
#pragma unroll
  for (int mi = 0; mi < 4; ++mi)
#pragma unroll
    for (int ni = 0; ni < 4; ++ni) acc[mi][ni] = (f32x4){0.f, 0.f, 0.f, 0.f};

#define STAGE(Abuf, Bbuf, kk)                          \
  do {                                                 \
    gload16(gA + (kk),          Abuf + lofs);          \
    gload16(gA + (kk) + 16 * K, Abuf + lofs + 512);    \
    gload16(gB + (kk),          Bbuf + lofs);          \
    gload16(gB + (kk) + 16 * K, Bbuf + lofs + 512);    \
  } while (0)

  // prologue: chunks 0,1 in flight (8 loads)
  STAGE(as0, bs0, 0);
  STAGE(as1, bs1, 32);
  for (int j = 0; j < 11; ++j) {
    int k0 = j * 64;
    WAIT4_BAR();                       // chunk 2j landed (newest 4 stay in flight)
    gemm_compute(as0, bs0, wm, wn, l16, g, acc);
    BAR();                             // everyone done reading as0/bs0
    STAGE(as0, bs0, k0 + 64);          // chunk 2j+2
    WAIT4_BAR();                       // chunk 2j+1 landed
    gemm_compute(as1, bs1, wm, wn, l16, g, acc);
    BAR();
    STAGE(as1, bs1, k0 + 96);          // chunk 2j+3
  }
  // peel: chunks 22 (k=704, as0) and 23 (k=736, as1)
  WAIT4_BAR();
  gemm_compute(as0, bs0, wm, wn, l16, g, acc);
  WAIT0_BAR();
  gemm_compute(as1, bs1, wm, wn, l16, g, acc);
#undef STAGE

  // epilogue: bias + scatter to q/k/vT (bf16)
  int tbase = m0 & 1023;
  int b = m0 >> 10;
  int g4 = g * 4;
#pragma unroll
  for (int ni = 0; ni < 4; ++ni) {
    int n = n0 + wn + ni * 16 + l16;
    float bv = bias[n];
    int region = n / 768;
    int c = n - region * 768;
    int h = c >> 6, d = c & 63;
    int bh = b * 12 + h;
#pragma unroll
    for (int mi = 0; mi < 4; ++mi) {
      int t0 = tbase + wm + mi * 16 + g4;
      if (region == 2) {
        u16x4 pv;
#pragma unroll
        for (int r = 0; r < 4; ++r) pv[r] = f2bf(acc[mi][ni][r] + bv);
        *reinterpret_cast<u16x4*>(vTb + ((size_t)bh * 64 + d) * 1024 + t0) = pv;
      } else {
        u16* dst = (region == 0) ? qb : kb;
#pragma unroll
        for (int r = 0; r < 4; ++r)
          dst[((size_t)bh * 1024 + t0 + r) * 64 + d] = f2bf(acc[mi][ni][r] + bv);
      }
    }
  }
}

// ---------------- causal relu attention ----------------
// y[b,h,q,:] = sum_{k<=q} relu(scale * q.k) * v[k]
// 32 q-rows/wave, KVBLK=64: 32 MFMAs + 16 b128 loads per iter, ~8.5 iters avg.
// Order per iter t: issue V(t) + K(t+1) loads -> pack P(t) (consumes s2c) ->
// QK^T(t+1) overwrites s2c (fills LDS write->read gap) -> read P -> PV(t).
__global__ __launch_bounds__(256) void attn_kernel(
    const u16* __restrict__ qb, const u16* __restrict__ kb,
    const u16* __restrict__ vTb, float* __restrict__ out) {
  __shared__ __align__(16) u16 plds[4][32 * 72];    // 32 q-rows x (64 keys + 8 pad)
  int lane = threadIdx.x & 63;
  int wave = threadIdx.x >> 6;
  int bh = blockIdx.x;                           // 0..95
  int q0 = (7 - blockIdx.y) * 128 + wave * 32;   // heaviest blocks first
  int b = bh / 12, h = bh - b * 12;
  const u16* Q  = qb  + (size_t)bh * 65536;
  const u16* Kp = kb  + (size_t)bh * 65536;
  const u16* Vt = vTb + (size_t)bh * 65536;
  int l16 = lane & 15, g = lane >> 4;
  u16* pw = &plds[wave][0];

  bf16x8 qf[2][2];
#pragma unroll
  for (int qi = 0; qi < 2; ++qi)
#pragma unroll
    for (int ks = 0; ks < 2; ++ks)
      qf[qi][ks] = __builtin_bit_cast(bf16x8,
          *reinterpret_cast<const u16x8*>(Q + (q0 + qi * 16 + l16) * 64 + ks * 32 + g * 8));

  f32x4 y[2][4];
#pragma unroll
  for (int mi = 0; mi < 2; ++mi)
#pragma unroll
    for (int ni = 0; ni < 4; ++ni) y[mi][ni] = (f32x4){0.f, 0.f, 0.f, 0.f};

  int ntile = ((q0 + 31) >> 6) + 1;      // 64-key tiles
  int qoff = q0 & 63;                    // 0 or 32: diag tile row offset

  // prologue: K(0) fragments, S^T(0)
  u16x8 kn[4][2];
#pragma unroll
  for (int kj = 0; kj < 4; ++kj)
#pragma unroll
    for (int ks = 0; ks < 2; ++ks)
      kn[kj][ks] = *reinterpret_cast<const u16x8*>(
          Kp + (kj * 16 + l16) * 64 + ks * 32 + g * 8);

  // S^T lane layout: q = qi*16 + l16 (col), key = kj*16 + g*4 + r (row)
  f32x4 s2c[4][2];
#pragma unroll
  for (int kj = 0; kj < 4; ++kj)
#pragma unroll
    for (int qi = 0; qi < 2; ++qi) s2c[kj][qi] = (f32x4){0.f, 0.f, 0.f, 0.f};
#pragma unroll
  for (int ks = 0; ks < 2; ++ks)
#pragma unroll
    for (int kj = 0; kj < 4; ++kj)
#pragma unroll
      for (int qi = 0; qi < 2; ++qi)
        s2c[kj][qi] = __builtin_amdgcn_mfma_f32_16x16x32_bf16(
            __builtin_bit_cast(bf16x8, kn[kj][ks]), qf[qi][ks], s2c[kj][qi], 0, 0, 0);

  for (int kt = 0; kt < ntile; ++kt) {
    int kb0 = kt << 6;
    bool notlast = (kt + 1 < ntile);

    // 1) issue V(t) loads (used at PV, ~300cy later)
    u16x8 vf[4][2];
#pragma unroll
    for (int ni = 0; ni < 4; ++ni)
#pragma unroll
      for (int kc = 0; kc < 2; ++kc)
        vf[ni][kc] = *reinterpret_cast<const u16x8*>(
            Vt + (ni * 16 + l16) * 1024 + kb0 + kc * 32 + g * 8);

    // 2) issue K(t+1) loads
    if (notlast) {
      int kb2 = kb0 + 64;
#pragma unroll
      for (int kj = 0; kj < 4; ++kj)
#pragma unroll
        for (int ks = 0; ks < 2; ++ks)
          kn[kj][ks] = *reinterpret_cast<const u16x8*>(
              Kp + (kb2 + kj * 16 + l16) * 64 + ks * 32 + g * 8);
    }

    // 3) pack P(t): scale, relu, diag mask; LDS write (b64 per (kj,qi))
    bool diag = !notlast;
#pragma unroll
    for (int kj = 0; kj < 4; ++kj)
#pragma unroll
      for (int qi = 0; qi < 2; ++qi) {
        u16x4 pv;
#pragma unroll
        for (int r = 0; r < 4; ++r) {
          float v = fmaxf(s2c[kj][qi][r] * 0.125f, 0.f);
          if (diag && (kj * 16 + g * 4 + r > qoff + qi * 16 + l16)) v = 0.f;
          pv[r] = f2bf(v);
        }
        *reinterpret_cast<u16x4*>(pw + (qi * 16 + l16) * 72 + kj * 16 + g * 4) = pv;
      }

    __builtin_amdgcn_s_setprio(1);
    // 4) QK^T(t+1) into s2c (pack already consumed it) — fills write->read gap
    if (notlast) {
#pragma unroll
      for (int kj = 0; kj < 4; ++kj)
#pragma unroll
        for (int qi = 0; qi < 2; ++qi) s2c[kj][qi] = (f32x4){0.f, 0.f, 0.f, 0.f};
#pragma unroll
      for (int ks = 0; ks < 2; ++ks)
#pragma unroll
        for (int kj = 0; kj < 4; ++kj)
#pragma unroll
          for (int qi = 0; qi < 2; ++qi)
            s2c[kj][qi] = __builtin_amdgcn_mfma_f32_16x16x32_bf16(
                __builtin_bit_cast(bf16x8, kn[kj][ks]), qf[qi][ks], s2c[kj][qi], 0, 0, 0);
    }

    // 5) read P(t), PV(t)
    bf16x8 pa[2][2];
#pragma unroll
    for (int mi = 0; mi < 2; ++mi)
#pragma unroll
      for (int kc = 0; kc < 2; ++kc)
        pa[mi][kc] = __builtin_bit_cast(bf16x8,
            *reinterpret_cast<const u16x8*>(pw + (mi * 16 + l16) * 72 + kc * 32 + g * 8));
#pragma unroll
    for (int kc = 0; kc < 2; ++kc)
#pragma unroll
      for (int ni = 0; ni < 4; ++ni)
#pragma unroll
        for (int mi = 0; mi < 2; ++mi)
          y[mi][ni] = __builtin_amdgcn_mfma_f32_16x16x32_bf16(
              pa[mi][kc], __builtin_bit_cast(bf16x8, vf[ni][kc]), y[mi][ni], 0, 0, 0);
    __builtin_amdgcn_s_setprio(0);
  }

  // out[b, t, h*64+d] f32
  float* outp = out + (size_t)b * 1024 * 768 + (size_t)h * 64;
#pragma unroll
  for (int mi = 0; mi < 2; ++mi)
#pragma unroll
    for (int r = 0; r < 4; ++r) {
      int t = q0 + mi * 16 + g * 4 + r;
#pragma unroll
      for (int ni = 0; ni < 4; ++ni)
        outp[(size_t)t * 768 + ni * 16 + l16] = y[mi][ni][r];
    }
}

extern "C" void kernel_launch(void* const* d_in, const int* in_sizes, int n_in,
                              void* d_out, int out_size, void* d_ws, size_t ws_size,
                              hipStream_t stream) {
  const float* x    = (const float*)d_in[0];
  const float* W    = (const float*)d_in[1];
  const float* bias = (const float*)d_in[2];
  float* out = (float*)d_out;
  char* ws = (char*)d_ws;

  // ws layout (bytes): xb 12.58MB | WbT 3.54MB | qb 12.58MB | kb 12.58MB | vTb 12.58MB
  u16* xb  = (u16*)(ws);
  u16* WbT = (u16*)(ws + 12582912);
  u16* qb  = (u16*)(ws + 16121856);
  u16* kb  = (u16*)(ws + 28704768);
  u16* vTb = (u16*)(ws + 41287680);

  hipLaunchKernelGGL(cvt_x_kernel, dim3(3072), dim3(256), 0, stream, x, xb);
  hipLaunchKernelGGL(cvt_wT_kernel, dim3(9, 192), dim3(256), 0, stream, W, WbT);
  hipLaunchKernelGGL(gemm_qkv_kernel, dim3(64, 18), dim3(256), 0, stream,
                     xb, WbT, bias, qb, kb, vTb);
  hipLaunchKernelGGL(attn_kernel, dim3(96, 8), dim3(256), 0, stream, qb, kb, vTb, out);
}